// Round 1
// baseline (3050.489 us; speedup 1.0000x reference)
//
#include <hip/hip_runtime.h>
#include <hip/hip_bf16.h>

#define N_NODES 100000
#define N_EDGES 20000
#define NNZ     1600000

// ---------------------------------------------------------------- CSR build

__global__ void count_deg(const int* __restrict__ node_idx,
                          const int* __restrict__ edge_idx,
                          int* __restrict__ cntN, int* __restrict__ cntE) {
    int i = blockIdx.x * 256 + threadIdx.x;
    if (i < NNZ) {
        atomicAdd(&cntE[edge_idx[i]], 1);
        atomicAdd(&cntN[node_idx[i]], 1);
    }
}

// single-block exclusive scan (Hillis-Steele per 1024 chunk with carry)
__global__ __launch_bounds__(1024)
void scan_excl(const int* __restrict__ cnt, int n,
               int* __restrict__ off, float* __restrict__ inv) {
    __shared__ int tmp[1024];
    __shared__ int carry_s;
    if (threadIdx.x == 0) carry_s = 0;
    __syncthreads();
    int nIter = (n + 1023) / 1024;
    for (int it = 0; it < nIter; ++it) {
        int i = it * 1024 + threadIdx.x;
        int v = (i < n) ? cnt[i] : 0;
        tmp[threadIdx.x] = v;
        __syncthreads();
        for (int s = 1; s < 1024; s <<= 1) {
            int t = (threadIdx.x >= (unsigned)s) ? tmp[threadIdx.x - s] : 0;
            __syncthreads();
            tmp[threadIdx.x] += t;
            __syncthreads();
        }
        int carry = carry_s;
        if (i < n) {
            off[i] = carry + tmp[threadIdx.x] - v;   // exclusive
            inv[i] = (v > 0) ? 1.0f / (float)v : 0.0f;
        }
        int tot = tmp[1023];
        __syncthreads();
        if (threadIdx.x == 0) carry_s = carry + tot;
        __syncthreads();
    }
    if (threadIdx.x == 0) off[n] = carry_s;
}

__global__ void copy_int(const int* __restrict__ src, int* __restrict__ dst, int n) {
    int i = blockIdx.x * 256 + threadIdx.x;
    if (i < n) dst[i] = src[i];
}

__global__ void fill_csr(const int* __restrict__ node_idx,
                         const int* __restrict__ edge_idx,
                         int* __restrict__ curE, int* __restrict__ curN,
                         int* __restrict__ csrE, int* __restrict__ csrN) {
    int i = blockIdx.x * 256 + threadIdx.x;
    if (i < NNZ) {
        int e = edge_idx[i], n = node_idx[i];
        int pe = atomicAdd(&curE[e], 1);
        csrE[pe] = n;                 // node rows grouped by edge
        int pn = atomicAdd(&curN[n], 1);
        csrN[pn] = e;                 // edge rows grouped by node
    }
}

// ---------------------------------------------------------------- fp32 GEMM
// C[M,N] = A[M,K] * W[K,N]; 128x128 tile, 8x8 microtile, BK=16
#define TM 128
#define TN 128
#define BK 16

__global__ __launch_bounds__(256)
void gemm_f32(const float* __restrict__ A, const float* __restrict__ W,
              float* __restrict__ C, int M, int K, int N) {
    __shared__ float As[BK][TM + 4];   // k-major so a-frag loads are float4
    __shared__ float Bs[BK][TN + 4];
    int tid = threadIdx.x;
    int tx = tid % 16;       // N dir
    int ty = tid / 16;       // M dir
    int row0 = blockIdx.x * TM;
    int col0 = blockIdx.y * TN;
    float acc[8][8] = {};
    for (int k0 = 0; k0 < K; k0 += BK) {
        for (int l = tid; l < TM * BK; l += 256) {
            int r = l / BK, c = l % BK;
            int gr = row0 + r, gk = k0 + c;
            As[c][r] = (gr < M && gk < K) ? A[(size_t)gr * K + gk] : 0.0f;
        }
        for (int l = tid; l < BK * TN; l += 256) {
            int r = l / TN, c = l % TN;
            int gk = k0 + r;
            Bs[r][c] = (gk < K) ? W[(size_t)gk * N + col0 + c] : 0.0f;
        }
        __syncthreads();
        #pragma unroll
        for (int kk = 0; kk < BK; kk++) {
            float a[8], b[8];
            #pragma unroll
            for (int i = 0; i < 8; i++) a[i] = As[kk][ty * 8 + i];
            #pragma unroll
            for (int j = 0; j < 8; j++) b[j] = Bs[kk][tx * 8 + j];
            #pragma unroll
            for (int i = 0; i < 8; i++)
                #pragma unroll
                for (int j = 0; j < 8; j++)
                    acc[i][j] += a[i] * b[j];
        }
        __syncthreads();
    }
    for (int i = 0; i < 8; i++) {
        int gr = row0 + ty * 8 + i;
        if (gr < M) {
            float4* p = (float4*)&C[(size_t)gr * N + col0 + tx * 8];
            p[0] = make_float4(acc[i][0], acc[i][1], acc[i][2], acc[i][3]);
            p[1] = make_float4(acc[i][4], acc[i][5], acc[i][6], acc[i][7]);
        }
    }
}

// ------------------------------------------------------- segment aggregation
// e[edge] = Binv[edge] * sum_{members} X[node_row]   (block = F threads)
__global__ void edge_agg(const float* __restrict__ X, const int* __restrict__ offE,
                         const int* __restrict__ csrE, const float* __restrict__ Binv,
                         float* __restrict__ E, int F) {
    int e = blockIdx.x;
    int f = threadIdx.x;
    int s = offE[e], t = offE[e + 1];
    float acc = 0.f;
    int j = s;
    for (; j + 3 < t; j += 4) {
        int r0 = csrE[j], r1 = csrE[j + 1], r2 = csrE[j + 2], r3 = csrE[j + 3];
        float v0 = X[(size_t)r0 * F + f];
        float v1 = X[(size_t)r1 * F + f];
        float v2 = X[(size_t)r2 * F + f];
        float v3 = X[(size_t)r3 * F + f];
        acc += v0 + v1 + v2 + v3;
    }
    for (; j < t; j++) acc += X[(size_t)csrE[j] * F + f];
    E[(size_t)e * F + f] = acc * Binv[e];
}

// out[node] = lrelu( Dinv[node] * sum_{members} Ebuf[edge_row] + bias )
__global__ void node_agg(const float* __restrict__ Ebuf, const int* __restrict__ offN,
                         const int* __restrict__ csrN, const float* __restrict__ Dinv,
                         const float* __restrict__ bias, float* __restrict__ out,
                         int F, int do_lrelu) {
    int n = blockIdx.x;
    int f = threadIdx.x;
    int s = offN[n], t = offN[n + 1];
    float acc = 0.f;
    int j = s;
    for (; j + 3 < t; j += 4) {
        int r0 = csrN[j], r1 = csrN[j + 1], r2 = csrN[j + 2], r3 = csrN[j + 3];
        float v0 = Ebuf[(size_t)r0 * F + f];
        float v1 = Ebuf[(size_t)r1 * F + f];
        float v2 = Ebuf[(size_t)r2 * F + f];
        float v3 = Ebuf[(size_t)r3 * F + f];
        acc += v0 + v1 + v2 + v3;
    }
    for (; j < t; j++) acc += Ebuf[(size_t)csrN[j] * F + f];
    float v = acc * Dinv[n] + bias[f];
    if (do_lrelu) v = (v > 0.f) ? v : 0.01f * v;
    out[(size_t)n * F + f] = v;
}

// ------------------------------------------------------------- attention pool
// logits[n] = dot(H[n,:128], aW) + aB ; per-block max partials
__global__ __launch_bounds__(256)
void logits_kernel(const float* __restrict__ H, const float* __restrict__ aW,
                   const float* __restrict__ aB, float* __restrict__ logits,
                   float* __restrict__ pmax, int N) {
    int lane = threadIdx.x & 63;
    int wave = threadIdx.x >> 6;
    int waveGlobal = blockIdx.x * 4 + wave;
    int stride = gridDim.x * 4;
    float2 w2 = ((const float2*)aW)[lane];
    float lmax = -1e30f;
    float ab = aB[0];
    for (int n = waveGlobal; n < N; n += stride) {
        float2 h2 = ((const float2*)(H + (size_t)n * 128))[lane];
        float d = h2.x * w2.x + h2.y * w2.y;
        #pragma unroll
        for (int s = 32; s > 0; s >>= 1) d += __shfl_xor(d, s, 64);
        float lg = d + ab;
        if (lane == 0) logits[n] = lg;
        lmax = fmaxf(lmax, lg);
    }
    __shared__ float wmax[4];
    if (lane == 0) wmax[wave] = lmax;
    __syncthreads();
    if (threadIdx.x == 0) {
        float m = fmaxf(fmaxf(wmax[0], wmax[1]), fmaxf(wmax[2], wmax[3]));
        pmax[blockIdx.x] = m;
    }
}

__global__ __launch_bounds__(256)
void reduce_max(const float* __restrict__ pmax, int n, float* __restrict__ gmax) {
    __shared__ float sm[256];
    float m = -1e30f;
    for (int i = threadIdx.x; i < n; i += 256) m = fmaxf(m, pmax[i]);
    sm[threadIdx.x] = m;
    __syncthreads();
    for (int s = 128; s > 0; s >>= 1) {
        if (threadIdx.x < (unsigned)s) sm[threadIdx.x] = fmaxf(sm[threadIdx.x], sm[threadIdx.x + s]);
        __syncthreads();
    }
    if (threadIdx.x == 0) *gmax = sm[0];
}

__global__ __launch_bounds__(128)
void weighted_sum(const float* __restrict__ H, const float* __restrict__ logits,
                  const float* __restrict__ gmax, float* __restrict__ gacc,
                  float* __restrict__ gsum, int N) {
    int f = threadIdx.x;
    float mx = *gmax;
    float acc = 0.f, ls = 0.f;
    for (int n = blockIdx.x; n < N; n += gridDim.x) {
        float w = __expf(logits[n] - mx);
        acc += w * H[(size_t)n * 128 + f];
        if (f == 0) ls += w;
    }
    atomicAdd(&gacc[f], acc);
    if (f == 0) atomicAdd(gsum, ls);
}

__global__ __launch_bounds__(128)
void finalize(const float* __restrict__ gacc, const float* __restrict__ gsum,
              float* __restrict__ out) {
    int f = threadIdx.x;
    out[f] = gacc[f] / gsum[0];
}

// ---------------------------------------------------------------- launch

extern "C" void kernel_launch(void* const* d_in, const int* in_sizes, int n_in,
                              void* d_out, int out_size, void* d_ws, size_t ws_size,
                              hipStream_t stream) {
    const float* x        = (const float*)d_in[0];
    const int*   node_idx = (const int*)d_in[1];
    const int*   edge_idx = node_idx + NNZ;
    const float* W1 = (const float*)d_in[2];
    const float* b1 = (const float*)d_in[3];
    const float* W2 = (const float*)d_in[4];
    const float* b2 = (const float*)d_in[5];
    const float* W3 = (const float*)d_in[6];
    const float* b3 = (const float*)d_in[7];
    const float* aW = (const float*)d_in[8];
    const float* aB = (const float*)d_in[9];
    float* out = (float*)d_out;

    char* ws = (char*)d_ws;
    size_t off = 0;
    auto take = [&](size_t bytes) -> char* {
        char* r = ws + off;
        off = (off + bytes + 255) & ~(size_t)255;
        return r;
    };

    // counters (one contiguous zeroed region)
    char* cnt_base = take((size_t)(N_EDGES + N_NODES) * 4);
    int* cntE = (int*)cnt_base;
    int* cntN = cntE + N_EDGES;
    int*   offE = (int*)take((size_t)(N_EDGES + 1) * 4);
    int*   offN = (int*)take((size_t)(N_NODES + 1) * 4);
    int*   curE = (int*)take((size_t)N_EDGES * 4);
    int*   curN = (int*)take((size_t)N_NODES * 4);
    float* Binv = (float*)take((size_t)N_EDGES * 4);
    float* Dinv = (float*)take((size_t)N_NODES * 4);
    int*   csrE = (int*)take((size_t)NNZ * 4);
    int*   csrN = (int*)take((size_t)NNZ * 4);
    float* bufA = (float*)take((size_t)N_NODES * 256 * 4);   // xw
    float* bufB = (float*)take((size_t)N_NODES * 256 * 4);   // h
    float* ebuf = (float*)take((size_t)N_EDGES * 256 * 4);
    float* logits = (float*)take((size_t)N_NODES * 4);
    float* pmax = (float*)take(400 * 4);
    char* acc_base = take((128 + 1) * 4);                    // gacc + gsum, zeroed
    float* gacc = (float*)acc_base;
    float* gsum = gacc + 128;
    float* gmax = (float*)take(4);

    // zero accumulators (ws is poisoned 0xAA before every launch)
    hipMemsetAsync(cnt_base, 0, (size_t)(N_EDGES + N_NODES) * 4, stream);
    hipMemsetAsync(acc_base, 0, (128 + 1) * 4, stream);

    // CSR build (once; shared by all 3 layers)
    count_deg<<<NNZ / 256, 256, 0, stream>>>(node_idx, edge_idx, cntN, cntE);
    scan_excl<<<1, 1024, 0, stream>>>(cntE, N_EDGES, offE, Binv);
    scan_excl<<<1, 1024, 0, stream>>>(cntN, N_NODES, offN, Dinv);
    copy_int<<<(N_EDGES + 255) / 256, 256, 0, stream>>>(offE, curE, N_EDGES);
    copy_int<<<(N_NODES + 255) / 256, 256, 0, stream>>>(offN, curN, N_NODES);
    fill_csr<<<NNZ / 256, 256, 0, stream>>>(node_idx, edge_idx, curE, curN, csrE, csrN);

    const int MB = (N_NODES + TM - 1) / TM;   // 782

    // layer 1: x[100000,300] @ W1[300,256]
    gemm_f32<<<dim3(MB, 2), 256, 0, stream>>>(x, W1, bufA, N_NODES, 300, 256);
    edge_agg<<<N_EDGES, 256, 0, stream>>>(bufA, offE, csrE, Binv, ebuf, 256);
    node_agg<<<N_NODES, 256, 0, stream>>>(ebuf, offN, csrN, Dinv, b1, bufB, 256, 1);

    // layer 2: h[100000,256] @ W2[256,256]
    gemm_f32<<<dim3(MB, 2), 256, 0, stream>>>(bufB, W2, bufA, N_NODES, 256, 256);
    edge_agg<<<N_EDGES, 256, 0, stream>>>(bufA, offE, csrE, Binv, ebuf, 256);
    node_agg<<<N_NODES, 256, 0, stream>>>(ebuf, offN, csrN, Dinv, b2, bufB, 256, 1);

    // layer 3: h[100000,256] @ W3[256,128], no lrelu
    gemm_f32<<<dim3(MB, 1), 256, 0, stream>>>(bufB, W3, bufA, N_NODES, 256, 128);
    edge_agg<<<N_EDGES, 128, 0, stream>>>(bufA, offE, csrE, Binv, ebuf, 128);
    node_agg<<<N_NODES, 128, 0, stream>>>(ebuf, offN, csrN, Dinv, b3, bufB, 128, 0);

    // attention pooling
    logits_kernel<<<400, 256, 0, stream>>>(bufB, aW, aB, logits, pmax, N_NODES);
    reduce_max<<<1, 256, 0, stream>>>(pmax, 400, gmax);
    weighted_sum<<<512, 128, 0, stream>>>(bufB, logits, gmax, gacc, gsum, N_NODES);
    finalize<<<1, 128, 0, stream>>>(gacc, gsum, out);
}

// Round 2
// 1368.492 us; speedup vs baseline: 2.2291x; 2.2291x over previous
//
#include <hip/hip_runtime.h>
#include <hip/hip_bf16.h>
#include <string.h>

#define N_NODES 100000
#define N_EDGES 20000
#define NNZ     1600000

// ------------------------------------------------------------ bf16 helpers

__device__ __forceinline__ unsigned short f2bf(float f) {
    unsigned int u = __float_as_uint(f);
    unsigned int r = (u + 0x7fffu + ((u >> 16) & 1u)) >> 16;   // RNE
    return (unsigned short)r;
}
__device__ __forceinline__ float bflo(unsigned int v) { return __uint_as_float(v << 16); }
__device__ __forceinline__ float bfhi(unsigned int v) { return __uint_as_float(v & 0xffff0000u); }

__device__ __forceinline__ void async_copy16(const void* g, void* l) {
    __builtin_amdgcn_global_load_lds((const __attribute__((address_space(1))) void*)g,
                                     (__attribute__((address_space(3))) void*)l, 16, 0, 0);
}

typedef __attribute__((ext_vector_type(8))) short bf16x8;
typedef __attribute__((ext_vector_type(4))) float f32x4;

// ---------------------------------------------------------------- CSR build

__global__ void count_deg(const int* __restrict__ node_idx,
                          const int* __restrict__ edge_idx,
                          int* __restrict__ cntN, int* __restrict__ cntE) {
    int i = blockIdx.x * 256 + threadIdx.x;
    if (i < NNZ) {
        atomicAdd(&cntE[edge_idx[i]], 1);
        atomicAdd(&cntN[node_idx[i]], 1);
    }
}

// two-level scan: pass1 block sums (1024 elems/block), pass2 scan of block
// sums (single block), pass3 per-block rescan + offsets/inverse-degree
__global__ __launch_bounds__(256)
void scan_pass1(const int* __restrict__ cnt, int n, int* __restrict__ bsum) {
    int b = blockIdx.x, t = threadIdx.x;
    int base = b * 1024 + t * 4;
    int s = 0;
    #pragma unroll
    for (int q = 0; q < 4; q++) { int i = base + q; if (i < n) s += cnt[i]; }
    __shared__ int ts[256];
    ts[t] = s; __syncthreads();
    for (int st = 128; st > 0; st >>= 1) {
        if (t < st) ts[t] += ts[t + st];
        __syncthreads();
    }
    if (t == 0) bsum[b] = ts[0];
}

__global__ __launch_bounds__(1024)
void scan_pass2(int* __restrict__ bsum, int nb, int n, int* __restrict__ off) {
    __shared__ int tmp[1024];
    int t = threadIdx.x;
    int v = (t < nb) ? bsum[t] : 0;
    tmp[t] = v; __syncthreads();
    for (int st = 1; st < 1024; st <<= 1) {
        int x = (t >= st) ? tmp[t - st] : 0;
        __syncthreads();
        tmp[t] += x;
        __syncthreads();
    }
    if (t < nb) bsum[t] = tmp[t] - v;   // exclusive block offsets
    if (t == 1023) off[n] = tmp[1023];  // total
}

__global__ __launch_bounds__(256)
void scan_pass3(const int* __restrict__ cnt, const int* __restrict__ boff, int n,
                int* __restrict__ off, float* __restrict__ inv) {
    int b = blockIdx.x, t = threadIdx.x;
    int base = b * 1024 + t * 4;
    int v[4]; int s = 0;
    #pragma unroll
    for (int q = 0; q < 4; q++) { int i = base + q; v[q] = (i < n) ? cnt[i] : 0; s += v[q]; }
    __shared__ int ts[256];
    ts[t] = s; __syncthreads();
    for (int st = 1; st < 256; st <<= 1) {
        int x = (t >= st) ? ts[t - st] : 0;
        __syncthreads();
        ts[t] += x;
        __syncthreads();
    }
    int excl = boff[b] + ts[t] - s;
    #pragma unroll
    for (int q = 0; q < 4; q++) {
        int i = base + q;
        if (i < n) {
            off[i] = excl;
            inv[i] = (v[q] > 0) ? 1.0f / (float)v[q] : 0.0f;
            excl += v[q];
        }
    }
}

__global__ void copy_int(const int* __restrict__ src, int* __restrict__ dst, int n) {
    int i = blockIdx.x * 256 + threadIdx.x;
    if (i < n) dst[i] = src[i];
}

__global__ void fill_csr(const int* __restrict__ node_idx,
                         const int* __restrict__ edge_idx,
                         int* __restrict__ curE, int* __restrict__ curN,
                         int* __restrict__ csrE, int* __restrict__ csrN) {
    int i = blockIdx.x * 256 + threadIdx.x;
    if (i < NNZ) {
        int e = edge_idx[i], n = node_idx[i];
        int pe = atomicAdd(&curE[e], 1);
        csrE[pe] = n;
        int pn = atomicAdd(&curN[n], 1);
        csrN[pn] = e;
    }
}

// ------------------------------------------------------------ prep kernels

// x [N_NODES,300] fp32 -> xb [N_NODES,320] bf16 zero-padded
__global__ void convert_pad_x(const float* __restrict__ x, unsigned short* __restrict__ xb) {
    int idx = blockIdx.x * 256 + threadIdx.x;
    if (idx < N_NODES * 320) {
        int r = idx / 320, k = idx - r * 320;
        xb[idx] = (k < 300) ? f2bf(x[(size_t)r * 300 + k]) : (unsigned short)0;
    }
}

// W [K,N] fp32 -> Wt [N,Kp] bf16 (transposed, zero-padded K)
__global__ void transpose_w(const float* __restrict__ W, unsigned short* __restrict__ Wt,
                            int K, int N, int Kp) {
    int n = blockIdx.x;
    for (int k = threadIdx.x; k < Kp; k += 256)
        Wt[(size_t)n * Kp + k] = (k < K) ? f2bf(W[(size_t)k * N + n]) : (unsigned short)0;
}

// ------------------------------------------------------------ bf16 MFMA GEMM
// C[M,N] = A[M,Kp] * Bt[N,Kp]^T ; 128x128 tile, 4 waves, 16x16x32 MFMA
__global__ __launch_bounds__(256)
void gemm_bf16(const unsigned short* __restrict__ A,
               const unsigned short* __restrict__ Bt,
               unsigned short* __restrict__ C,
               int M, int Kp, int N) {
    __shared__ unsigned short As[128 * 32];
    __shared__ unsigned short Bs[128 * 32];
    int tid = threadIdx.x;
    int lane = tid & 63;
    int w = tid >> 6;
    int row0 = blockIdx.x * 128;
    int col0 = blockIdx.y * 128;
    int wm = w & 1, wn = w >> 1;

    f32x4 acc[4][4];
    #pragma unroll
    for (int i = 0; i < 4; i++)
        #pragma unroll
        for (int j = 0; j < 4; j++) acc[i][j] = (f32x4){0.f, 0.f, 0.f, 0.f};

    int sr = lane >> 2;   // row within 16-row staging group
    int sc = lane & 3;    // 16B chunk within 64B row

    for (int k0 = 0; k0 < Kp; k0 += 32) {
        // stage A tile rows [w*32, w*32+32), 16 rows (1 KB) per wave-call
        #pragma unroll
        for (int c = 0; c < 2; c++) {
            int r = w * 32 + c * 16 + sr;
            int gr = row0 + r; if (gr >= M) gr = M - 1;   // clamp tail (garbage rows unused)
            const unsigned short* g = A + (size_t)gr * Kp + k0 + sc * 8;
            async_copy16(g, (void*)(As + (w * 32 + c * 16) * 32));
        }
        #pragma unroll
        for (int c = 0; c < 2; c++) {
            int r = w * 32 + c * 16 + sr;
            const unsigned short* g = Bt + (size_t)(col0 + r) * Kp + k0 + sc * 8;
            async_copy16(g, (void*)(Bs + (w * 32 + c * 16) * 32));
        }
        __syncthreads();

        bf16x8 a[4], b[4];
        #pragma unroll
        for (int i = 0; i < 4; i++)
            a[i] = *(const bf16x8*)(As + (wm * 64 + i * 16 + (lane & 15)) * 32 + (lane >> 4) * 8);
        #pragma unroll
        for (int j = 0; j < 4; j++)
            b[j] = *(const bf16x8*)(Bs + (wn * 64 + j * 16 + (lane & 15)) * 32 + (lane >> 4) * 8);
        #pragma unroll
        for (int i = 0; i < 4; i++)
            #pragma unroll
            for (int j = 0; j < 4; j++)
                acc[i][j] = __builtin_amdgcn_mfma_f32_16x16x32_bf16(a[i], b[j], acc[i][j], 0, 0, 0);
        __syncthreads();
    }

    // C/D layout: col = lane&15, row = (lane>>4)*4 + reg  (m89-verified)
    int crow = (lane >> 4) * 4;
    int ccol = lane & 15;
    #pragma unroll
    for (int i = 0; i < 4; i++)
        #pragma unroll
        for (int r = 0; r < 4; r++) {
            int gr = row0 + wm * 64 + i * 16 + crow + r;
            if (gr < M) {
                #pragma unroll
                for (int j = 0; j < 4; j++) {
                    int gc = col0 + wn * 64 + j * 16 + ccol;
                    C[(size_t)gr * N + gc] = f2bf(acc[i][j][r]);
                }
            }
        }
}

// ------------------------------------------------------- segment aggregation
// e[edge] = Binv[edge] * sum X[node_row] ; bf16 in, bf16 out, fp32 accumulate
// block = F/2 threads (each handles 2 features via packed u32)
__global__ void edge_agg_bf16(const unsigned short* __restrict__ X, const int* __restrict__ offE,
                              const int* __restrict__ csrE, const float* __restrict__ Binv,
                              unsigned short* __restrict__ E, int F) {
    int e = blockIdx.x;
    int f2 = threadIdx.x;
    int s = offE[e], t = offE[e + 1];
    float a0 = 0.f, a1 = 0.f;
    int j = s;
    for (; j + 3 < t; j += 4) {
        int r0 = csrE[j], r1 = csrE[j + 1], r2 = csrE[j + 2], r3 = csrE[j + 3];
        unsigned int v0 = *(const unsigned int*)(X + (size_t)r0 * F + f2 * 2);
        unsigned int v1 = *(const unsigned int*)(X + (size_t)r1 * F + f2 * 2);
        unsigned int v2 = *(const unsigned int*)(X + (size_t)r2 * F + f2 * 2);
        unsigned int v3 = *(const unsigned int*)(X + (size_t)r3 * F + f2 * 2);
        a0 += (bflo(v0) + bflo(v1)) + (bflo(v2) + bflo(v3));
        a1 += (bfhi(v0) + bfhi(v1)) + (bfhi(v2) + bfhi(v3));
    }
    for (; j < t; j++) {
        unsigned int v = *(const unsigned int*)(X + (size_t)csrE[j] * F + f2 * 2);
        a0 += bflo(v); a1 += bfhi(v);
    }
    float bi = Binv[e];
    unsigned int o = ((unsigned int)f2bf(a1 * bi) << 16) | (unsigned int)f2bf(a0 * bi);
    *(unsigned int*)(E + (size_t)e * F + f2 * 2) = o;
}

// out[node] = lrelu?( Dinv * sum Ebuf[edge_row] + bias ) ; bf16 or fp32 out
__global__ void node_agg_bf16(const unsigned short* __restrict__ Ebuf, const int* __restrict__ offN,
                              const int* __restrict__ csrN, const float* __restrict__ Dinv,
                              const float* __restrict__ bias,
                              unsigned short* __restrict__ outB, float* __restrict__ outF,
                              int F, int do_lrelu) {
    int n = blockIdx.x;
    int f2 = threadIdx.x;
    int s = offN[n], t = offN[n + 1];
    float a0 = 0.f, a1 = 0.f;
    int j = s;
    for (; j + 3 < t; j += 4) {
        int r0 = csrN[j], r1 = csrN[j + 1], r2 = csrN[j + 2], r3 = csrN[j + 3];
        unsigned int v0 = *(const unsigned int*)(Ebuf + (size_t)r0 * F + f2 * 2);
        unsigned int v1 = *(const unsigned int*)(Ebuf + (size_t)r1 * F + f2 * 2);
        unsigned int v2 = *(const unsigned int*)(Ebuf + (size_t)r2 * F + f2 * 2);
        unsigned int v3 = *(const unsigned int*)(Ebuf + (size_t)r3 * F + f2 * 2);
        a0 += (bflo(v0) + bflo(v1)) + (bflo(v2) + bflo(v3));
        a1 += (bfhi(v0) + bfhi(v1)) + (bfhi(v2) + bfhi(v3));
    }
    for (; j < t; j++) {
        unsigned int v = *(const unsigned int*)(Ebuf + (size_t)csrN[j] * F + f2 * 2);
        a0 += bflo(v); a1 += bfhi(v);
    }
    float di = Dinv[n];
    float o0 = a0 * di + bias[f2 * 2];
    float o1 = a1 * di + bias[f2 * 2 + 1];
    if (do_lrelu) {
        o0 = (o0 > 0.f) ? o0 : 0.01f * o0;
        o1 = (o1 > 0.f) ? o1 : 0.01f * o1;
    }
    if (outB) {
        unsigned int o = ((unsigned int)f2bf(o1) << 16) | (unsigned int)f2bf(o0);
        *(unsigned int*)(outB + (size_t)n * F + f2 * 2) = o;
    } else {
        outF[(size_t)n * F + f2 * 2]     = o0;
        outF[(size_t)n * F + f2 * 2 + 1] = o1;
    }
}

// ------------------------------------------------------------- attention pool

__global__ __launch_bounds__(256)
void logits_kernel(const float* __restrict__ H, const float* __restrict__ aW,
                   const float* __restrict__ aB, float* __restrict__ logits,
                   float* __restrict__ pmax, int N) {
    int lane = threadIdx.x & 63;
    int wave = threadIdx.x >> 6;
    int waveGlobal = blockIdx.x * 4 + wave;
    int stride = gridDim.x * 4;
    float2 w2 = ((const float2*)aW)[lane];
    float lmax = -1e30f;
    float ab = aB[0];
    for (int n = waveGlobal; n < N; n += stride) {
        float2 h2 = ((const float2*)(H + (size_t)n * 128))[lane];
        float d = h2.x * w2.x + h2.y * w2.y;
        #pragma unroll
        for (int s = 32; s > 0; s >>= 1) d += __shfl_xor(d, s, 64);
        float lg = d + ab;
        if (lane == 0) logits[n] = lg;
        lmax = fmaxf(lmax, lg);
    }
    __shared__ float wmax[4];
    if (lane == 0) wmax[wave] = lmax;
    __syncthreads();
    if (threadIdx.x == 0) {
        float m = fmaxf(fmaxf(wmax[0], wmax[1]), fmaxf(wmax[2], wmax[3]));
        pmax[blockIdx.x] = m;
    }
}

__global__ __launch_bounds__(256)
void reduce_max(const float* __restrict__ pmax, int n, float* __restrict__ gmax) {
    __shared__ float sm[256];
    float m = -1e30f;
    for (int i = threadIdx.x; i < n; i += 256) m = fmaxf(m, pmax[i]);
    sm[threadIdx.x] = m;
    __syncthreads();
    for (int s = 128; s > 0; s >>= 1) {
        if (threadIdx.x < (unsigned)s) sm[threadIdx.x] = fmaxf(sm[threadIdx.x], sm[threadIdx.x + s]);
        __syncthreads();
    }
    if (threadIdx.x == 0) *gmax = sm[0];
}

__global__ __launch_bounds__(128)
void weighted_sum(const float* __restrict__ H, const float* __restrict__ logits,
                  const float* __restrict__ gmax, float* __restrict__ gacc,
                  float* __restrict__ gsum, int N) {
    int f = threadIdx.x;
    float mx = *gmax;
    float acc = 0.f, ls = 0.f;
    for (int n = blockIdx.x; n < N; n += gridDim.x) {
        float w = __expf(logits[n] - mx);
        acc += w * H[(size_t)n * 128 + f];
        if (f == 0) ls += w;
    }
    atomicAdd(&gacc[f], acc);
    if (f == 0) atomicAdd(gsum, ls);
}

__global__ __launch_bounds__(128)
void finalize(const float* __restrict__ gacc, const float* __restrict__ gsum,
              float* __restrict__ out) {
    int f = threadIdx.x;
    out[f] = gacc[f] / gsum[0];
}

// ---------------------------------------------------------------- launch

extern "C" void kernel_launch(void* const* d_in, const int* in_sizes, int n_in,
                              void* d_out, int out_size, void* d_ws, size_t ws_size,
                              hipStream_t stream) {
    const float* x        = (const float*)d_in[0];
    const int*   node_idx = (const int*)d_in[1];
    const int*   edge_idx = node_idx + NNZ;
    const float* W1 = (const float*)d_in[2];
    const float* b1 = (const float*)d_in[3];
    const float* W2 = (const float*)d_in[4];
    const float* b2 = (const float*)d_in[5];
    const float* W3 = (const float*)d_in[6];
    const float* b3 = (const float*)d_in[7];
    const float* aW = (const float*)d_in[8];
    const float* aB = (const float*)d_in[9];
    float* out = (float*)d_out;

    char* ws = (char*)d_ws;
    size_t off = 0;
    auto take = [&](size_t bytes) -> char* {
        char* r = ws + off;
        off = (off + bytes + 255) & ~(size_t)255;
        return r;
    };

    char* cnt_base = take((size_t)(N_EDGES + N_NODES) * 4);
    int* cntE = (int*)cnt_base;
    int* cntN = cntE + N_EDGES;
    int*   offE = (int*)take((size_t)(N_EDGES + 1) * 4);
    int*   offN = (int*)take((size_t)(N_NODES + 1) * 4);
    int*   curE = (int*)take((size_t)N_EDGES * 4);
    int*   curN = (int*)take((size_t)N_NODES * 4);
    float* Binv = (float*)take((size_t)N_EDGES * 4);
    float* Dinv = (float*)take((size_t)N_NODES * 4);
    int*   bsum = (int*)take(1024 * 4);
    int*   csrE = (int*)take((size_t)NNZ * 4);
    int*   csrN = (int*)take((size_t)NNZ * 4);

    unsigned short* xb  = (unsigned short*)take((size_t)N_NODES * 320 * 2);  // also reused as h3 (fp32,128)
    unsigned short* Wt1 = (unsigned short*)take((size_t)256 * 320 * 2);
    unsigned short* Wt2 = (unsigned short*)take((size_t)256 * 256 * 2);
    unsigned short* Wt3 = (unsigned short*)take((size_t)128 * 256 * 2);
    unsigned short* xw  = (unsigned short*)take((size_t)N_NODES * 256 * 2);  // gemm out
    unsigned short* hb  = (unsigned short*)take((size_t)N_NODES * 256 * 2);  // node_agg bf16 out
    unsigned short* eb  = (unsigned short*)take((size_t)N_EDGES * 256 * 2);  // edge table
    float* h3 = (float*)xb;                                                  // [N_NODES,128] fp32

    float* logits = (float*)take((size_t)N_NODES * 4);
    float* pmax   = (float*)take(400 * 4);
    char* acc_base = take((128 + 1) * 4);
    float* gacc = (float*)acc_base;
    float* gsum = gacc + 128;
    float* gmax = (float*)take(4);

    hipMemsetAsync(cnt_base, 0, (size_t)(N_EDGES + N_NODES) * 4, stream);
    hipMemsetAsync(acc_base, 0, (128 + 1) * 4, stream);

    // ---- CSR build (shared by all 3 layers)
    count_deg<<<NNZ / 256, 256, 0, stream>>>(node_idx, edge_idx, cntN, cntE);
    const int nbE = (N_EDGES + 1023) / 1024;   // 20
    const int nbN = (N_NODES + 1023) / 1024;   // 98
    scan_pass1<<<nbE, 256, 0, stream>>>(cntE, N_EDGES, bsum);
    scan_pass2<<<1, 1024, 0, stream>>>(bsum, nbE, N_EDGES, offE);
    scan_pass3<<<nbE, 256, 0, stream>>>(cntE, bsum, N_EDGES, offE, Binv);
    scan_pass1<<<nbN, 256, 0, stream>>>(cntN, N_NODES, bsum);
    scan_pass2<<<1, 1024, 0, stream>>>(bsum, nbN, N_NODES, offN);
    scan_pass3<<<nbN, 256, 0, stream>>>(cntN, bsum, N_NODES, offN, Dinv);
    copy_int<<<(N_EDGES + 255) / 256, 256, 0, stream>>>(offE, curE, N_EDGES);
    copy_int<<<(N_NODES + 255) / 256, 256, 0, stream>>>(offN, curN, N_NODES);
    fill_csr<<<NNZ / 256, 256, 0, stream>>>(node_idx, edge_idx, curE, curN, csrE, csrN);

    // ---- prep: bf16 conversions
    convert_pad_x<<<(N_NODES * 320 + 255) / 256, 256, 0, stream>>>(x, xb);
    transpose_w<<<256, 256, 0, stream>>>(W1, Wt1, 300, 256, 320);
    transpose_w<<<256, 256, 0, stream>>>(W2, Wt2, 256, 256, 256);
    transpose_w<<<128, 256, 0, stream>>>(W3, Wt3, 256, 128, 256);

    const int MB = (N_NODES + 127) / 128;   // 782

    // ---- layer 1
    gemm_bf16<<<dim3(MB, 2), 256, 0, stream>>>(xb, Wt1, xw, N_NODES, 320, 256);
    edge_agg_bf16<<<N_EDGES, 128, 0, stream>>>(xw, offE, csrE, Binv, eb, 256);
    node_agg_bf16<<<N_NODES, 128, 0, stream>>>(eb, offN, csrN, Dinv, b1, hb, nullptr, 256, 1);

    // ---- layer 2
    gemm_bf16<<<dim3(MB, 2), 256, 0, stream>>>(hb, Wt2, xw, N_NODES, 256, 256);
    edge_agg_bf16<<<N_EDGES, 128, 0, stream>>>(xw, offE, csrE, Binv, eb, 256);
    node_agg_bf16<<<N_NODES, 128, 0, stream>>>(eb, offN, csrN, Dinv, b2, hb, nullptr, 256, 1);

    // ---- layer 3 (N=128, fp32 output for attention precision)
    gemm_bf16<<<dim3(MB, 1), 256, 0, stream>>>(hb, Wt3, xw, N_NODES, 256, 128);
    edge_agg_bf16<<<N_EDGES, 64, 0, stream>>>(xw, offE, csrE, Binv, eb, 128);
    node_agg_bf16<<<N_NODES, 64, 0, stream>>>(eb, offN, csrN, Dinv, b3, nullptr, h3, 128, 0);

    // ---- attention pooling (fp32)
    logits_kernel<<<400, 256, 0, stream>>>(h3, aW, aB, logits, pmax, N_NODES);
    reduce_max<<<1, 256, 0, stream>>>(pmax, 400, gmax);
    weighted_sum<<<512, 128, 0, stream>>>(h3, logits, gmax, gacc, gsum, N_NODES);
    finalize<<<1, 128, 0, stream>>>(gacc, gsum, out);
}

// Round 3
// 1052.402 us; speedup vs baseline: 2.8986x; 1.3004x over previous
//
#include <hip/hip_runtime.h>
#include <hip/hip_bf16.h>
#include <string.h>

#define N_NODES 100000
#define N_EDGES 20000
#define NNZ     1600000

// CSR-build binning params
#define CHUNK   8192           // entries per bin block
#define NBE     157            // edge buckets: ceil(20000/128), bshift=7, kshift=17
#define NBN     391            // node buckets: ceil(100000/256), bshift=8, kshift=15
#define NBLK_BIN ((NNZ + CHUNK - 1) / CHUNK)   // 196

// ------------------------------------------------------------ bf16 helpers

__device__ __forceinline__ unsigned short f2bf(float f) {
    unsigned int u = __float_as_uint(f);
    unsigned int r = (u + 0x7fffu + ((u >> 16) & 1u)) >> 16;   // RNE
    return (unsigned short)r;
}
__device__ __forceinline__ float bflo(unsigned int v) { return __uint_as_float(v << 16); }
__device__ __forceinline__ float bfhi(unsigned int v) { return __uint_as_float(v & 0xffff0000u); }

__device__ __forceinline__ void async_copy16(const void* g, void* l) {
    __builtin_amdgcn_global_load_lds((const __attribute__((address_space(1))) void*)g,
                                     (__attribute__((address_space(3))) void*)l, 16, 0, 0);
}

typedef __attribute__((ext_vector_type(8))) short bf16x8;
typedef __attribute__((ext_vector_type(4))) float f32x4;

// ---------------------------------------------------- CSR build (bucketed)

// coarse bucket histograms for both directions in one pass
__global__ __launch_bounds__(256)
void hist_buckets(const int* __restrict__ node_idx, const int* __restrict__ edge_idx,
                  int* __restrict__ bcntE, int* __restrict__ bcntN) {
    __shared__ int hE[NBE];
    __shared__ int hN[NBN];
    int t = threadIdx.x;
    for (int i = t; i < NBE; i += 256) hE[i] = 0;
    for (int i = t; i < NBN; i += 256) hN[i] = 0;
    __syncthreads();
    long base = (long)blockIdx.x * CHUNK;
    #pragma unroll 4
    for (int k = 0; k < CHUNK / 256; k++) {
        long i = base + t + k * 256;
        if (i < NNZ) {
            atomicAdd(&hE[edge_idx[i] >> 7], 1);
            atomicAdd(&hN[node_idx[i] >> 8], 1);
        }
    }
    __syncthreads();
    for (int i = t; i < NBE; i += 256) if (hE[i]) atomicAdd(&bcntE[i], hE[i]);
    for (int i = t; i < NBN; i += 256) if (hN[i]) atomicAdd(&bcntN[i], hN[i]);
}

// exclusive scan of <=512 bucket counts; writes base[0..n] and cursor copy
__global__ __launch_bounds__(512)
void small_scan(const int* __restrict__ cnt, int n,
                int* __restrict__ base, int* __restrict__ cursor) {
    __shared__ int tmp[512];
    int t = threadIdx.x;
    int v = (t < n) ? cnt[t] : 0;
    tmp[t] = v; __syncthreads();
    for (int s = 1; s < 512; s <<= 1) {
        int x = (t >= s) ? tmp[t - s] : 0;
        __syncthreads();
        tmp[t] += x;
        __syncthreads();
    }
    if (t < n) { int e = tmp[t] - v; base[t] = e; cursor[t] = e; }
    if (t == 0) base[n] = tmp[511];   // total
}

// bin entries into bucket-grouped staging (packed (key<<kshift)|val u32)
__global__ __launch_bounds__(256)
void bin_pass(const int* __restrict__ key_idx, const int* __restrict__ val_idx,
              int kshift, int bshift, int nbuck,
              int* __restrict__ cursor, unsigned int* __restrict__ staged) {
    __shared__ int hist[512];
    __shared__ int gstart[512];
    int t = threadIdx.x;
    for (int i = t; i < nbuck; i += 256) hist[i] = 0;
    __syncthreads();
    long base = (long)blockIdx.x * CHUNK;
    for (int k = 0; k < CHUNK / 256; k++) {
        long i = base + t + k * 256;
        if (i < NNZ) atomicAdd(&hist[key_idx[i] >> bshift], 1);
    }
    __syncthreads();
    for (int i = t; i < nbuck; i += 256)
        gstart[i] = hist[i] ? atomicAdd(&cursor[i], hist[i]) : 0;
    __syncthreads();
    for (int i = t; i < nbuck; i += 256) hist[i] = 0;   // reuse as local cursor
    __syncthreads();
    for (int k = 0; k < CHUNK / 256; k++) {
        long i = base + t + k * 256;
        if (i < NNZ) {
            int key = key_idx[i], val = val_idx[i];
            int b = key >> bshift;
            int pos = gstart[b] + atomicAdd(&hist[b], 1);
            staged[pos] = ((unsigned int)key << kshift) | (unsigned int)val;
        }
    }
}

// per bucket: count per key, local scan -> off/inv, scatter -> csr
__global__ __launch_bounds__(256)
void build_csr(const unsigned int* __restrict__ staged, const int* __restrict__ bbase,
               int kshift, int bshift, int nkey,
               int* __restrict__ off, float* __restrict__ inv, int* __restrict__ csr) {
    __shared__ int cnt[256];
    __shared__ int cur[256];
    int b = blockIdx.x, t = threadIdx.x;
    int kpb = 1 << bshift;          // keys per bucket (128 or 256)
    int key0 = b << bshift;
    unsigned int vmask = (1u << kshift) - 1u;
    if (t < kpb) cnt[t] = 0;
    __syncthreads();
    int s = bbase[b], e = bbase[b + 1];
    for (int j = s + t; j < e; j += 256)
        atomicAdd(&cnt[(int)(staged[j] >> kshift) - key0], 1);
    __syncthreads();
    int v = (t < kpb) ? cnt[t] : 0;
    cur[t] = v; __syncthreads();
    for (int st = 1; st < 256; st <<= 1) {
        int x = (t >= st) ? cur[t - st] : 0;
        __syncthreads();
        cur[t] += x;
        __syncthreads();
    }
    int excl = cur[t] - v;
    __syncthreads();
    if (t < kpb) {
        int key = key0 + t;
        if (key < nkey) {
            off[key] = s + excl;
            inv[key] = (v > 0) ? 1.0f / (float)v : 0.0f;
        }
        cur[t] = excl;
    }
    __syncthreads();
    for (int j = s + t; j < e; j += 256) {
        unsigned int pk = staged[j];
        int k = (int)(pk >> kshift) - key0;
        int pos = s + atomicAdd(&cur[k], 1);
        csr[pos] = (int)(pk & vmask);
    }
    if (b == 0 && t == 0) off[nkey] = NNZ;
}

// ------------------------------------------------------------ prep kernels

__global__ void convert_pad_x(const float* __restrict__ x, unsigned short* __restrict__ xb) {
    int idx = blockIdx.x * 256 + threadIdx.x;
    if (idx < N_NODES * 320) {
        int r = idx / 320, k = idx - r * 320;
        xb[idx] = (k < 300) ? f2bf(x[(size_t)r * 300 + k]) : (unsigned short)0;
    }
}

__global__ void transpose_w(const float* __restrict__ W, unsigned short* __restrict__ Wt,
                            int K, int N, int Kp) {
    int n = blockIdx.x;
    for (int k = threadIdx.x; k < Kp; k += 256)
        Wt[(size_t)n * Kp + k] = (k < K) ? f2bf(W[(size_t)k * N + n]) : (unsigned short)0;
}

// ------------------------------------------------------------ bf16 MFMA GEMM

__global__ __launch_bounds__(256)
void gemm_bf16(const unsigned short* __restrict__ A,
               const unsigned short* __restrict__ Bt,
               unsigned short* __restrict__ C,
               int M, int Kp, int N) {
    __shared__ unsigned short As[128 * 32];
    __shared__ unsigned short Bs[128 * 32];
    int tid = threadIdx.x;
    int lane = tid & 63;
    int w = tid >> 6;
    int row0 = blockIdx.x * 128;
    int col0 = blockIdx.y * 128;
    int wm = w & 1, wn = w >> 1;

    f32x4 acc[4][4];
    #pragma unroll
    for (int i = 0; i < 4; i++)
        #pragma unroll
        for (int j = 0; j < 4; j++) acc[i][j] = (f32x4){0.f, 0.f, 0.f, 0.f};

    int sr = lane >> 2;
    int sc = lane & 3;

    for (int k0 = 0; k0 < Kp; k0 += 32) {
        #pragma unroll
        for (int c = 0; c < 2; c++) {
            int r = w * 32 + c * 16 + sr;
            int gr = row0 + r; if (gr >= M) gr = M - 1;
            const unsigned short* g = A + (size_t)gr * Kp + k0 + sc * 8;
            async_copy16(g, (void*)(As + (w * 32 + c * 16) * 32));
        }
        #pragma unroll
        for (int c = 0; c < 2; c++) {
            int r = w * 32 + c * 16 + sr;
            const unsigned short* g = Bt + (size_t)(col0 + r) * Kp + k0 + sc * 8;
            async_copy16(g, (void*)(Bs + (w * 32 + c * 16) * 32));
        }
        __syncthreads();

        bf16x8 a[4], b[4];
        #pragma unroll
        for (int i = 0; i < 4; i++)
            a[i] = *(const bf16x8*)(As + (wm * 64 + i * 16 + (lane & 15)) * 32 + (lane >> 4) * 8);
        #pragma unroll
        for (int j = 0; j < 4; j++)
            b[j] = *(const bf16x8*)(Bs + (wn * 64 + j * 16 + (lane & 15)) * 32 + (lane >> 4) * 8);
        #pragma unroll
        for (int i = 0; i < 4; i++)
            #pragma unroll
            for (int j = 0; j < 4; j++)
                acc[i][j] = __builtin_amdgcn_mfma_f32_16x16x32_bf16(a[i], b[j], acc[i][j], 0, 0, 0);
        __syncthreads();
    }

    int crow = (lane >> 4) * 4;
    int ccol = lane & 15;
    #pragma unroll
    for (int i = 0; i < 4; i++)
        #pragma unroll
        for (int r = 0; r < 4; r++) {
            int gr = row0 + wm * 64 + i * 16 + crow + r;
            if (gr < M) {
                #pragma unroll
                for (int j = 0; j < 4; j++) {
                    int gc = col0 + wn * 64 + j * 16 + ccol;
                    C[(size_t)gr * N + gc] = f2bf(acc[i][j][r]);
                }
            }
        }
}

// ------------------------------------------------------- segment aggregation

__global__ void edge_agg_bf16(const unsigned short* __restrict__ X, const int* __restrict__ offE,
                              const int* __restrict__ csrE, const float* __restrict__ Binv,
                              unsigned short* __restrict__ E, int F) {
    int e = blockIdx.x;
    int f2 = threadIdx.x;
    int s = offE[e], t = offE[e + 1];
    float a0 = 0.f, a1 = 0.f;
    int j = s;
    for (; j + 3 < t; j += 4) {
        int r0 = csrE[j], r1 = csrE[j + 1], r2 = csrE[j + 2], r3 = csrE[j + 3];
        unsigned int v0 = *(const unsigned int*)(X + (size_t)r0 * F + f2 * 2);
        unsigned int v1 = *(const unsigned int*)(X + (size_t)r1 * F + f2 * 2);
        unsigned int v2 = *(const unsigned int*)(X + (size_t)r2 * F + f2 * 2);
        unsigned int v3 = *(const unsigned int*)(X + (size_t)r3 * F + f2 * 2);
        a0 += (bflo(v0) + bflo(v1)) + (bflo(v2) + bflo(v3));
        a1 += (bfhi(v0) + bfhi(v1)) + (bfhi(v2) + bfhi(v3));
    }
    for (; j < t; j++) {
        unsigned int v = *(const unsigned int*)(X + (size_t)csrE[j] * F + f2 * 2);
        a0 += bflo(v); a1 += bfhi(v);
    }
    float bi = Binv[e];
    unsigned int o = ((unsigned int)f2bf(a1 * bi) << 16) | (unsigned int)f2bf(a0 * bi);
    *(unsigned int*)(E + (size_t)e * F + f2 * 2) = o;
}

__global__ void node_agg_bf16(const unsigned short* __restrict__ Ebuf, const int* __restrict__ offN,
                              const int* __restrict__ csrN, const float* __restrict__ Dinv,
                              const float* __restrict__ bias,
                              unsigned short* __restrict__ outB, float* __restrict__ outF,
                              int F, int do_lrelu) {
    int n = blockIdx.x;
    int f2 = threadIdx.x;
    int s = offN[n], t = offN[n + 1];
    float a0 = 0.f, a1 = 0.f;
    int j = s;
    for (; j + 3 < t; j += 4) {
        int r0 = csrN[j], r1 = csrN[j + 1], r2 = csrN[j + 2], r3 = csrN[j + 3];
        unsigned int v0 = *(const unsigned int*)(Ebuf + (size_t)r0 * F + f2 * 2);
        unsigned int v1 = *(const unsigned int*)(Ebuf + (size_t)r1 * F + f2 * 2);
        unsigned int v2 = *(const unsigned int*)(Ebuf + (size_t)r2 * F + f2 * 2);
        unsigned int v3 = *(const unsigned int*)(Ebuf + (size_t)r3 * F + f2 * 2);
        a0 += (bflo(v0) + bflo(v1)) + (bflo(v2) + bflo(v3));
        a1 += (bfhi(v0) + bfhi(v1)) + (bfhi(v2) + bfhi(v3));
    }
    for (; j < t; j++) {
        unsigned int v = *(const unsigned int*)(Ebuf + (size_t)csrN[j] * F + f2 * 2);
        a0 += bflo(v); a1 += bfhi(v);
    }
    float di = Dinv[n];
    float o0 = a0 * di + bias[f2 * 2];
    float o1 = a1 * di + bias[f2 * 2 + 1];
    if (do_lrelu) {
        o0 = (o0 > 0.f) ? o0 : 0.01f * o0;
        o1 = (o1 > 0.f) ? o1 : 0.01f * o1;
    }
    if (outB) {
        unsigned int o = ((unsigned int)f2bf(o1) << 16) | (unsigned int)f2bf(o0);
        *(unsigned int*)(outB + (size_t)n * F + f2 * 2) = o;
    } else {
        outF[(size_t)n * F + f2 * 2]     = o0;
        outF[(size_t)n * F + f2 * 2 + 1] = o1;
    }
}

// ------------------------------------------------------------- attention pool

__global__ __launch_bounds__(256)
void logits_kernel(const float* __restrict__ H, const float* __restrict__ aW,
                   const float* __restrict__ aB, float* __restrict__ logits,
                   float* __restrict__ pmax, int N) {
    int lane = threadIdx.x & 63;
    int wave = threadIdx.x >> 6;
    int waveGlobal = blockIdx.x * 4 + wave;
    int stride = gridDim.x * 4;
    float2 w2 = ((const float2*)aW)[lane];
    float lmax = -1e30f;
    float ab = aB[0];
    for (int n = waveGlobal; n < N; n += stride) {
        float2 h2 = ((const float2*)(H + (size_t)n * 128))[lane];
        float d = h2.x * w2.x + h2.y * w2.y;
        #pragma unroll
        for (int s = 32; s > 0; s >>= 1) d += __shfl_xor(d, s, 64);
        float lg = d + ab;
        if (lane == 0) logits[n] = lg;
        lmax = fmaxf(lmax, lg);
    }
    __shared__ float wmax[4];
    if (lane == 0) wmax[wave] = lmax;
    __syncthreads();
    if (threadIdx.x == 0) {
        float m = fmaxf(fmaxf(wmax[0], wmax[1]), fmaxf(wmax[2], wmax[3]));
        pmax[blockIdx.x] = m;
    }
}

__global__ __launch_bounds__(256)
void reduce_max(const float* __restrict__ pmax, int n, float* __restrict__ gmax) {
    __shared__ float sm[256];
    float m = -1e30f;
    for (int i = threadIdx.x; i < n; i += 256) m = fmaxf(m, pmax[i]);
    sm[threadIdx.x] = m;
    __syncthreads();
    for (int s = 128; s > 0; s >>= 1) {
        if (threadIdx.x < (unsigned)s) sm[threadIdx.x] = fmaxf(sm[threadIdx.x], sm[threadIdx.x + s]);
        __syncthreads();
    }
    if (threadIdx.x == 0) *gmax = sm[0];
}

__global__ __launch_bounds__(128)
void weighted_sum(const float* __restrict__ H, const float* __restrict__ logits,
                  const float* __restrict__ gmax, float* __restrict__ gacc,
                  float* __restrict__ gsum, int N) {
    int f = threadIdx.x;
    float mx = *gmax;
    float acc = 0.f, ls = 0.f;
    for (int n = blockIdx.x; n < N; n += gridDim.x) {
        float w = __expf(logits[n] - mx);
        acc += w * H[(size_t)n * 128 + f];
        if (f == 0) ls += w;
    }
    atomicAdd(&gacc[f], acc);
    if (f == 0) atomicAdd(gsum, ls);
}

__global__ __launch_bounds__(128)
void finalize(const float* __restrict__ gacc, const float* __restrict__ gsum,
              float* __restrict__ out) {
    int f = threadIdx.x;
    out[f] = gacc[f] / gsum[0];
}

// ---------------------------------------------------------------- launch

extern "C" void kernel_launch(void* const* d_in, const int* in_sizes, int n_in,
                              void* d_out, int out_size, void* d_ws, size_t ws_size,
                              hipStream_t stream) {
    const float* x        = (const float*)d_in[0];
    const int*   node_idx = (const int*)d_in[1];
    const int*   edge_idx = node_idx + NNZ;
    const float* W1 = (const float*)d_in[2];
    const float* b1 = (const float*)d_in[3];
    const float* W2 = (const float*)d_in[4];
    const float* b2 = (const float*)d_in[5];
    const float* W3 = (const float*)d_in[6];
    const float* b3 = (const float*)d_in[7];
    const float* aW = (const float*)d_in[8];
    const float* aB = (const float*)d_in[9];
    float* out = (float*)d_out;

    char* ws = (char*)d_ws;
    size_t off = 0;
    auto take = [&](size_t bytes) -> char* {
        char* r = ws + off;
        off = (off + bytes + 255) & ~(size_t)255;
        return r;
    };

    // bucket counters (zeroed each launch)
    char* bcnt_base = take((size_t)(NBE + NBN) * 4);
    int* bcntE = (int*)bcnt_base;
    int* bcntN = bcntE + NBE;
    int* baseE = (int*)take((NBE + 1) * 4);
    int* baseN = (int*)take((NBN + 1) * 4);
    int* curEb = (int*)take(NBE * 4);
    int* curNb = (int*)take(NBN * 4);
    int*   offE = (int*)take((size_t)(N_EDGES + 1) * 4);
    int*   offN = (int*)take((size_t)(N_NODES + 1) * 4);
    float* Binv = (float*)take((size_t)N_EDGES * 4);
    float* Dinv = (float*)take((size_t)N_NODES * 4);
    int*   csrE = (int*)take((size_t)NNZ * 4);
    int*   csrN = (int*)take((size_t)NNZ * 4);

    unsigned short* xb  = (unsigned short*)take((size_t)N_NODES * 320 * 2);  // reused as h3 fp32
    unsigned short* Wt1 = (unsigned short*)take((size_t)256 * 320 * 2);
    unsigned short* Wt2 = (unsigned short*)take((size_t)256 * 256 * 2);
    unsigned short* Wt3 = (unsigned short*)take((size_t)128 * 256 * 2);
    unsigned short* xw  = (unsigned short*)take((size_t)N_NODES * 256 * 2);  // gemm out
    unsigned short* hb  = (unsigned short*)take((size_t)N_NODES * 256 * 2);
    unsigned short* eb  = (unsigned short*)take((size_t)N_EDGES * 256 * 2);
    float* h3 = (float*)xb;

    // staging aliases xw (dead until first gemm; stream order guarantees safety)
    unsigned int* stagedE = (unsigned int*)xw;
    unsigned int* stagedN = stagedE + NNZ;

    float* logits = (float*)take((size_t)N_NODES * 4);
    float* pmax   = (float*)take(400 * 4);
    char* acc_base = take((128 + 1) * 4);
    float* gacc = (float*)acc_base;
    float* gsum = gacc + 128;
    float* gmax = (float*)take(4);

    hipMemsetAsync(bcnt_base, 0, (size_t)(NBE + NBN) * 4, stream);
    hipMemsetAsync(acc_base, 0, (128 + 1) * 4, stream);

    // ---- CSR build (bucketed counting sort, both directions)
    hist_buckets<<<NBLK_BIN, 256, 0, stream>>>(node_idx, edge_idx, bcntE, bcntN);
    small_scan<<<1, 512, 0, stream>>>(bcntE, NBE, baseE, curEb);
    small_scan<<<1, 512, 0, stream>>>(bcntN, NBN, baseN, curNb);
    bin_pass<<<NBLK_BIN, 256, 0, stream>>>(edge_idx, node_idx, 17, 7, NBE, curEb, stagedE);
    bin_pass<<<NBLK_BIN, 256, 0, stream>>>(node_idx, edge_idx, 15, 8, NBN, curNb, stagedN);
    build_csr<<<NBE, 256, 0, stream>>>(stagedE, baseE, 17, 7, N_EDGES, offE, Binv, csrE);
    build_csr<<<NBN, 256, 0, stream>>>(stagedN, baseN, 15, 8, N_NODES, offN, Dinv, csrN);

    // ---- prep: bf16 conversions
    convert_pad_x<<<(N_NODES * 320 + 255) / 256, 256, 0, stream>>>(x, xb);
    transpose_w<<<256, 256, 0, stream>>>(W1, Wt1, 300, 256, 320);
    transpose_w<<<256, 256, 0, stream>>>(W2, Wt2, 256, 256, 256);
    transpose_w<<<128, 256, 0, stream>>>(W3, Wt3, 256, 128, 256);

    const int MB = (N_NODES + 127) / 128;   // 782

    // ---- layer 1
    gemm_bf16<<<dim3(MB, 2), 256, 0, stream>>>(xb, Wt1, xw, N_NODES, 320, 256);
    edge_agg_bf16<<<N_EDGES, 128, 0, stream>>>(xw, offE, csrE, Binv, eb, 256);
    node_agg_bf16<<<N_NODES, 128, 0, stream>>>(eb, offN, csrN, Dinv, b1, hb, nullptr, 256, 1);

    // ---- layer 2
    gemm_bf16<<<dim3(MB, 2), 256, 0, stream>>>(hb, Wt2, xw, N_NODES, 256, 256);
    edge_agg_bf16<<<N_EDGES, 128, 0, stream>>>(xw, offE, csrE, Binv, eb, 256);
    node_agg_bf16<<<N_NODES, 128, 0, stream>>>(eb, offN, csrN, Dinv, b2, hb, nullptr, 256, 1);

    // ---- layer 3 (fp32 output for attention precision)
    gemm_bf16<<<dim3(MB, 1), 256, 0, stream>>>(hb, Wt3, xw, N_NODES, 256, 128);
    edge_agg_bf16<<<N_EDGES, 64, 0, stream>>>(xw, offE, csrE, Binv, eb, 128);
    node_agg_bf16<<<N_NODES, 64, 0, stream>>>(eb, offN, csrN, Dinv, b3, nullptr, h3, 128, 0);

    // ---- attention pooling (fp32)
    logits_kernel<<<400, 256, 0, stream>>>(h3, aW, aB, logits, pmax, N_NODES);
    reduce_max<<<1, 256, 0, stream>>>(pmax, 400, gmax);
    weighted_sum<<<512, 128, 0, stream>>>(h3, logits, gmax, gacc, gsum, N_NODES);
    finalize<<<1, 128, 0, stream>>>(gacc, gsum, out);
}